// Round 1
// baseline (2925.102 us; speedup 1.0000x reference)
//
#include <hip/hip_runtime.h>
#include <math.h>

#define KD 3
#define KK 9
#define BB 8
#define CC 64
#define OO 64
#define HH 128
#define WW 128
#define HWSZ (HH*WW)
#define OPT 4  // output channels per thread in deform kernel

// ---------------- Kernel 1: offset (18ch) + mask (9ch) 3x3 conv ----------------
// grid: (HW/256, 27, B), block 256
__global__ __launch_bounds__(256) void conv_om(
    const float* __restrict__ x, const float* __restrict__ p_w, const float* __restrict__ p_b,
    const float* __restrict__ m_w, const float* __restrict__ m_b,
    float* __restrict__ offset_out, float* __restrict__ mask_out)
{
    __shared__ float sw[CC*KK];
    const int oc = blockIdx.y;      // 0..26
    const int b  = blockIdx.z;
    const float* wsrc = (oc < 18) ? (p_w + oc*CC*KK) : (m_w + (oc-18)*CC*KK);
    const float bias = (oc < 18) ? p_b[oc] : m_b[oc-18];
    for (int i = threadIdx.x; i < CC*KK; i += 256) sw[i] = wsrc[i];
    __syncthreads();

    const int pix = blockIdx.x*256 + threadIdx.x;
    const int h = pix / WW, w = pix % WW;
    const float* xb = x + (size_t)b*CC*HWSZ;
    float acc = bias;
    for (int ic = 0; ic < CC; ++ic) {
        const float* xp = xb + ic*HWSZ;
        const float* wp = sw + ic*KK;
        #pragma unroll
        for (int kh = 0; kh < 3; ++kh) {
            const int hy = h + kh - 1;
            const bool vy = (hy >= 0) & (hy < HH);
            #pragma unroll
            for (int kw = 0; kw < 3; ++kw) {
                const int wx = w + kw - 1;
                const bool v = vy & (wx >= 0) & (wx < WW);
                const float xv = v ? xp[hy*WW + wx] : 0.f;
                acc = fmaf(xv, wp[kh*3+kw], acc);
            }
        }
    }
    if (oc < 18) {
        offset_out[((size_t)b*18 + oc)*HWSZ + pix] = acc;
    } else {
        mask_out[((size_t)b*9 + (oc-18))*HWSZ + pix] = 1.f / (1.f + expf(-acc));
    }
}

// ---------------- Kernel 2: modulated deformable conv ----------------
// grid: (HW/256, O/OPT, B), block 256
__global__ __launch_bounds__(256) void deform_conv(
    const float* __restrict__ x, const float* __restrict__ offset,
    const float* __restrict__ mask, const float* __restrict__ dw,
    const float* __restrict__ db, float* __restrict__ out)
{
    __shared__ float sw[OPT*CC*KK]; // 2304 floats = 9.2 KB
    const int og = blockIdx.y;
    const int b  = blockIdx.z;
    for (int i = threadIdx.x; i < OPT*CC*KK; i += 256) sw[i] = dw[(size_t)og*OPT*CC*KK + i];
    __syncthreads();

    const int pix = blockIdx.x*256 + threadIdx.x;
    const int ho = pix / WW, wo = pix % WW;

    int   idx[KK][4];
    float wt [KK][4];
    const float* offb = offset + (size_t)b*18*HWSZ + pix;
    const float* mb   = mask   + (size_t)b*9*HWSZ  + pix;
    #pragma unroll
    for (int k = 0; k < KK; ++k) {
        const float dy = offb[(2*k  )*HWSZ];
        const float dx = offb[(2*k+1)*HWSZ];
        const float m  = mb[k*HWSZ];
        const float py = (float)(ho - 1 + k/3) + dy;
        const float px = (float)(wo - 1 + k%3) + dx;
        const float y0f = floorf(py), x0f = floorf(px);
        const int   iy0 = (int)y0f,   ix0 = (int)x0f;
        const float wy1 = py - y0f,   wx1 = px - x0f;
        const float wy0 = 1.f - wy1,  wx0 = 1.f - wx1;
        const bool vy0 = (iy0   >= 0) & (iy0   < HH);
        const bool vy1 = (iy0+1 >= 0) & (iy0+1 < HH);
        const bool vx0 = (ix0   >= 0) & (ix0   < WW);
        const bool vx1 = (ix0+1 >= 0) & (ix0+1 < WW);
        const int cy0 = min(max(iy0,  0), HH-1), cy1 = min(max(iy0+1, 0), HH-1);
        const int cx0 = min(max(ix0,  0), WW-1), cx1 = min(max(ix0+1, 0), WW-1);
        idx[k][0] = cy0*WW+cx0; wt[k][0] = wy0*wx0*((vy0&vx0)?m:0.f);
        idx[k][1] = cy0*WW+cx1; wt[k][1] = wy0*wx1*((vy0&vx1)?m:0.f);
        idx[k][2] = cy1*WW+cx0; wt[k][2] = wy1*wx0*((vy1&vx0)?m:0.f);
        idx[k][3] = cy1*WW+cx1; wt[k][3] = wy1*wx1*((vy1&vx1)?m:0.f);
    }

    float acc[OPT];
    #pragma unroll
    for (int i = 0; i < OPT; ++i) acc[i] = 0.f;

    const float* xb = x + (size_t)b*CC*HWSZ;
    for (int c = 0; c < CC; ++c) {
        const float* xp = xb + c*HWSZ;
        #pragma unroll
        for (int k = 0; k < KK; ++k) {
            const float v = wt[k][0]*xp[idx[k][0]] + wt[k][1]*xp[idx[k][1]]
                          + wt[k][2]*xp[idx[k][2]] + wt[k][3]*xp[idx[k][3]];
            #pragma unroll
            for (int i = 0; i < OPT; ++i)
                acc[i] = fmaf(v, sw[(i*CC + c)*KK + k], acc[i]);
        }
    }

    #pragma unroll
    for (int i = 0; i < OPT; ++i)
        out[((size_t)b*OO + og*OPT + i)*HWSZ + pix] = acc[i] + db[og*OPT + i];
}

extern "C" void kernel_launch(void* const* d_in, const int* in_sizes, int n_in,
                              void* d_out, int out_size, void* d_ws, size_t ws_size,
                              hipStream_t stream) {
    const float* x   = (const float*)d_in[0];
    const float* p_w = (const float*)d_in[1];
    const float* p_b = (const float*)d_in[2];
    const float* m_w = (const float*)d_in[3];
    const float* m_b = (const float*)d_in[4];
    const float* dw  = (const float*)d_in[5];
    const float* db  = (const float*)d_in[6];

    float* out        = (float*)d_out;                      // (B,O,H,W)
    float* offset_out = out + (size_t)BB*OO*HWSZ;           // (B,18,H,W)
    float* mask_ws    = (float*)d_ws;                       // (B,9,H,W)

    dim3 g1(HWSZ/256, 27, BB);
    conv_om<<<g1, 256, 0, stream>>>(x, p_w, p_b, m_w, m_b, offset_out, mask_ws);

    dim3 g2(HWSZ/256, OO/OPT, BB);
    deform_conv<<<g2, 256, 0, stream>>>(x, offset_out, mask_ws, dw, db, out);
}

// Round 2
// 857.073 us; speedup vs baseline: 3.4129x; 3.4129x over previous
//
#include <hip/hip_runtime.h>
#include <math.h>

#define KK 9
#define BB 8
#define CC 64
#define OO 64
#define HH 128
#define WW 128
#define HWSZ (HH*WW)

// Fully fused DCNv2: offset conv + mask conv + sigmoid + modulated deformable conv.
// One thread = one output pixel (owns ALL 64 output channels).
// grid = (HW/256, B), block = 256.
__global__ __launch_bounds__(256) void dcn_fused(
    const float* __restrict__ x,
    const float* __restrict__ p_w, const float* __restrict__ p_b,
    const float* __restrict__ m_w, const float* __restrict__ m_b,
    const float* __restrict__ dw,  const float* __restrict__ db,
    float* __restrict__ out, float* __restrict__ offset_out)
{
    const int pix = blockIdx.x*256 + threadIdx.x;
    const int b   = blockIdx.y;
    const int h = pix / WW, w = pix % WW;
    const float* xb = x + (size_t)b*CC*HWSZ;

    // ---------- phase 1: offset(18) + mask(9) 3x3 convs, accumulated in regs ----------
    float po[27];
    #pragma unroll
    for (int i = 0; i < 27; ++i) po[i] = 0.f;

    for (int c = 0; c < CC; ++c) {
        const float* xp = xb + c*HWSZ;
        float nb[9];
        #pragma unroll
        for (int kh = 0; kh < 3; ++kh) {
            const int hy = h + kh - 1;
            const bool vy = (hy >= 0) & (hy < HH);
            #pragma unroll
            for (int kw = 0; kw < 3; ++kw) {
                const int wx = w + kw - 1;
                nb[kh*3+kw] = (vy & (wx >= 0) & (wx < WW)) ? xp[hy*WW + wx] : 0.f;
            }
        }
        // wave-uniform weight addresses -> scalar loads, SGPR-operand FMAs
        const float* pwc = p_w + c*KK;   // p_w[oc][c][k], oc stride CC*KK
        #pragma unroll
        for (int oc = 0; oc < 18; ++oc) {
            #pragma unroll
            for (int k = 0; k < 9; ++k)
                po[oc] = fmaf(nb[k], pwc[oc*CC*KK + k], po[oc]);
        }
        const float* mwc = m_w + c*KK;
        #pragma unroll
        for (int oc = 0; oc < 9; ++oc) {
            #pragma unroll
            for (int k = 0; k < 9; ++k)
                po[18+oc] = fmaf(nb[k], mwc[oc*CC*KK + k], po[18+oc]);
        }
    }

    // biases, sigmoid, write offset output
    float dy[9], dx[9], mk[9];
    {
        float* offp = offset_out + (size_t)b*18*HWSZ + pix;
        #pragma unroll
        for (int k = 0; k < 9; ++k) {
            dy[k] = po[2*k]   + p_b[2*k];
            dx[k] = po[2*k+1] + p_b[2*k+1];
            offp[(2*k  )*HWSZ] = dy[k];
            offp[(2*k+1)*HWSZ] = dx[k];
            mk[k] = 1.f / (1.f + expf(-(po[18+k] + m_b[k])));
        }
    }

    // ---------- phase 2: bilinear corner tables ----------
    int   idx4[9][4];
    float wt4 [9][4];
    #pragma unroll
    for (int k = 0; k < 9; ++k) {
        const float py = (float)(h - 1 + k/3) + dy[k];
        const float px = (float)(w - 1 + k%3) + dx[k];
        const float y0f = floorf(py), x0f = floorf(px);
        const int   iy0 = (int)y0f,   ix0 = (int)x0f;
        const float wy1 = py - y0f,   wx1 = px - x0f;
        const float wy0 = 1.f - wy1,  wx0 = 1.f - wx1;
        const bool vy0 = (iy0   >= 0) & (iy0   < HH);
        const bool vy1 = (iy0+1 >= 0) & (iy0+1 < HH);
        const bool vx0 = (ix0   >= 0) & (ix0   < WW);
        const bool vx1 = (ix0+1 >= 0) & (ix0+1 < WW);
        const int cy0 = min(max(iy0,   0), HH-1), cy1 = min(max(iy0+1, 0), HH-1);
        const int cx0 = min(max(ix0,   0), WW-1), cx1 = min(max(ix0+1, 0), WW-1);
        idx4[k][0] = cy0*WW+cx0; wt4[k][0] = wy0*wx0*((vy0&vx0) ? mk[k] : 0.f);
        idx4[k][1] = cy0*WW+cx1; wt4[k][1] = wy0*wx1*((vy0&vx1) ? mk[k] : 0.f);
        idx4[k][2] = cy1*WW+cx0; wt4[k][2] = wy1*wx0*((vy1&vx0) ? mk[k] : 0.f);
        idx4[k][3] = cy1*WW+cx1; wt4[k][3] = wy1*wx1*((vy1&vx1) ? mk[k] : 0.f);
    }

    // ---------- phase 3: deformable conv, all 64 output channels ----------
    float acc[OO];
    #pragma unroll
    for (int o = 0; o < OO; ++o) acc[o] = 0.f;

    for (int c = 0; c < CC; ++c) {
        const float* xp = xb + c*HWSZ;
        float v[9];
        #pragma unroll
        for (int k = 0; k < 9; ++k)
            v[k] = wt4[k][0]*xp[idx4[k][0]] + wt4[k][1]*xp[idx4[k][1]]
                 + wt4[k][2]*xp[idx4[k][2]] + wt4[k][3]*xp[idx4[k][3]];

        const float* dwc = dw + c*KK;    // dw[o][c][k], o stride CC*KK — uniform addr
        #pragma unroll
        for (int o = 0; o < OO; ++o) {
            #pragma unroll
            for (int k = 0; k < 9; ++k)
                acc[o] = fmaf(v[k], dwc[o*CC*KK + k], acc[o]);
        }
    }

    float* op = out + (size_t)b*OO*HWSZ + pix;
    #pragma unroll
    for (int o = 0; o < OO; ++o)
        op[o*HWSZ] = acc[o] + db[o];
}

extern "C" void kernel_launch(void* const* d_in, const int* in_sizes, int n_in,
                              void* d_out, int out_size, void* d_ws, size_t ws_size,
                              hipStream_t stream) {
    const float* x   = (const float*)d_in[0];
    const float* p_w = (const float*)d_in[1];
    const float* p_b = (const float*)d_in[2];
    const float* m_w = (const float*)d_in[3];
    const float* m_b = (const float*)d_in[4];
    const float* dw  = (const float*)d_in[5];
    const float* db  = (const float*)d_in[6];

    float* out        = (float*)d_out;             // (B,O,H,W)
    float* offset_out = out + (size_t)BB*OO*HWSZ;  // (B,18,H,W)

    dim3 g(HWSZ/256, BB);
    dcn_fused<<<g, 256, 0, stream>>>(x, p_w, p_b, m_w, m_b, dw, db, out, offset_out);
}

// Round 3
// 401.381 us; speedup vs baseline: 7.2876x; 2.1353x over previous
//
#include <hip/hip_runtime.h>
#include <math.h>

#define KK 9
#define BB 8
#define CC 64
#define OO 64
#define HH 128
#define WW 128
#define HWSZ (HH*WW)

typedef _Float16 half8 __attribute__((ext_vector_type(8)));
typedef float    floatx4 __attribute__((ext_vector_type(4)));

// ws layout (f16): Wp[32][576] | Wd[9][64][64] | mask[B][9][HW]
#define WP_ELEMS (32*576)
#define WD_ELEMS (9*64*64)

// ---------------- repack weights to f16, MFMA-friendly layouts ----------------
__global__ __launch_bounds__(256) void repack(
    const float* __restrict__ p_w, const float* __restrict__ m_w,
    const float* __restrict__ d_w, _Float16* __restrict__ Wp, _Float16* __restrict__ Wd)
{
    int i = blockIdx.x*256 + threadIdx.x;
    if (i < WP_ELEMS) {
        int n = i / 576, r = i % 576;
        int k = r >> 6, c = r & 63;          // K-index = k*64 + c (tap-major)
        float v = 0.f;
        if (n < 18)      v = p_w[(n*CC + c)*KK + k];
        else if (n < 27) v = m_w[((n-18)*CC + c)*KK + k];
        Wp[i] = (_Float16)v;
    } else if (i < WP_ELEMS + WD_ELEMS) {
        int j = i - WP_ELEMS;
        int k = j / 4096, r = j % 4096, o = r >> 6, c = r & 63;  // Wd[k][o][c]
        Wd[j] = (_Float16)d_w[(o*CC + c)*KK + k];
    }
}

// ---------------- Kernel A: offset(18)+mask(9) conv via MFMA ----------------
// block 256 (4 waves) = 256 pixels; N=32 (27 used); K=576 tap-major
__global__ __launch_bounds__(256, 2) void dcn_offmask(
    const float* __restrict__ x, const _Float16* __restrict__ Wp,
    const float* __restrict__ p_b, const float* __restrict__ m_b,
    float* __restrict__ offset_out, _Float16* __restrict__ mask_h)
{
    __shared__ alignas(16) _Float16 A_sh[256][72];   // [px][c] per tap, 36864 B
    __shared__ alignas(16) _Float16 W_sh[32][72];    // [n][c]  per tap,  4608 B

    const int tid  = threadIdx.x;
    const int wv   = tid >> 6;
    const int lane = tid & 63;
    const int quad = lane >> 4;
    const int l15  = lane & 15;
    const int b    = blockIdx.y;
    const int pix0 = blockIdx.x * 256;
    const int pix  = pix0 + tid;
    const int h = pix >> 7, w = pix & 127;
    const float* xb = x + (size_t)b*CC*HWSZ;

    floatx4 acc[4][2];
    #pragma unroll
    for (int mt = 0; mt < 4; ++mt)
        #pragma unroll
        for (int nt = 0; nt < 2; ++nt) acc[mt][nt] = (floatx4)0.f;

    for (int k = 0; k < 9; ++k) {
        // stage weight slab W_sh[n][c] = Wp[n][k*64+c]
        {
            int n  = tid >> 3;
            int c0 = (tid & 7) * 8;
            *(half8*)&W_sh[n][c0] = *(const half8*)(Wp + n*576 + k*64 + c0);
        }
        // gather fixed-grid im2col for this tap
        const int hy = h + (k/3) - 1;
        const int wx = w + (k%3) - 1;
        const bool vld = (hy >= 0) & (hy < HH) & (wx >= 0) & (wx < WW);
        const float* xs = xb + hy*WW + wx;
        #pragma unroll
        for (int cb = 0; cb < 8; ++cb) {
            union { half8 v; _Float16 e[8]; } u;
            #pragma unroll
            for (int j = 0; j < 8; ++j) {
                float vv = 0.f;
                if (vld) vv = xs[(cb*8+j)*HWSZ];
                u.e[j] = (_Float16)vv;
            }
            *(half8*)&A_sh[tid][cb*8] = u.v;
        }
        __syncthreads();
        #pragma unroll
        for (int ks = 0; ks < 2; ++ks) {
            half8 bf[2];
            #pragma unroll
            for (int nt = 0; nt < 2; ++nt)
                bf[nt] = *(const half8*)&W_sh[nt*16 + l15][ks*32 + quad*8];
            #pragma unroll
            for (int mt = 0; mt < 4; ++mt) {
                half8 af = *(const half8*)&A_sh[wv*64 + mt*16 + l15][ks*32 + quad*8];
                acc[mt][0] = __builtin_amdgcn_mfma_f32_16x16x32_f16(af, bf[0], acc[mt][0], 0, 0, 0);
                acc[mt][1] = __builtin_amdgcn_mfma_f32_16x16x32_f16(af, bf[1], acc[mt][1], 0, 0, 0);
            }
        }
        __syncthreads();
    }

    // epilogue: transpose via LDS, add bias, sigmoid for mask
    float (*T)[260] = (float (*)[260])&A_sh[0][0];   // [27][260] f32 = 28080 B, fits
    #pragma unroll
    for (int nt = 0; nt < 2; ++nt) {
        const int ch = nt*16 + l15;
        if (ch < 27) {
            #pragma unroll
            for (int mt = 0; mt < 4; ++mt)
                #pragma unroll
                for (int r = 0; r < 4; ++r)
                    T[ch][wv*64 + mt*16 + quad*4 + r] = acc[mt][nt][r];
        }
    }
    __syncthreads();
    #pragma unroll
    for (int ch = 0; ch < 18; ++ch)
        offset_out[((size_t)b*18 + ch)*HWSZ + pix] = T[ch][tid] + p_b[ch];
    #pragma unroll
    for (int cm = 0; cm < 9; ++cm) {
        float v = T[18+cm][tid] + m_b[cm];
        mask_h[((size_t)b*9 + cm)*HWSZ + pix] = (_Float16)(1.f / (1.f + expf(-v)));
    }
}

// ---------------- Kernel B: modulated deformable conv via MFMA ----------------
// block 256 (4 waves) = 256 pixels; N=64; K=576 tap-major
__global__ __launch_bounds__(256, 2) void dcn_deform(
    const float* __restrict__ x, const float* __restrict__ offset,
    const _Float16* __restrict__ mask_h, const _Float16* __restrict__ Wd,
    const float* __restrict__ db, float* __restrict__ out)
{
    __shared__ alignas(16) _Float16 A_sh[256][72];   // 36864 B
    __shared__ alignas(16) _Float16 Wd_sh[64][72];   //  9216 B

    const int tid  = threadIdx.x;
    const int wv   = tid >> 6;
    const int lane = tid & 63;
    const int quad = lane >> 4;
    const int l15  = lane & 15;
    const int b    = blockIdx.y;
    const int pix0 = blockIdx.x * 256;
    const int pix  = pix0 + tid;
    const int h = pix >> 7, w = pix & 127;
    const float* xb = x + (size_t)b*CC*HWSZ;
    const float* offp = offset + (size_t)b*18*HWSZ + pix;
    const _Float16* mkp = mask_h + (size_t)b*9*HWSZ + pix;

    floatx4 acc[4][4];
    #pragma unroll
    for (int mt = 0; mt < 4; ++mt)
        #pragma unroll
        for (int nt = 0; nt < 4; ++nt) acc[mt][nt] = (floatx4)0.f;

    for (int k = 0; k < 9; ++k) {
        // stage weight slab Wd_sh[o][c] = Wd[k][o][c]
        {
            int o  = tid >> 2;
            int c0 = (tid & 3) * 16;
            const _Float16* src = Wd + k*4096 + o*64 + c0;
            *(half8*)&Wd_sh[o][c0]     = *(const half8*)src;
            *(half8*)&Wd_sh[o][c0 + 8] = *(const half8*)(src + 8);
        }
        // bilinear tables for this tap
        const float dyk = offp[(2*k  )*HWSZ];
        const float dxk = offp[(2*k+1)*HWSZ];
        const float mk  = (float)mkp[k*HWSZ];
        const float py = (float)(h - 1 + k/3) + dyk;
        const float px = (float)(w - 1 + k%3) + dxk;
        const float y0f = floorf(py), x0f = floorf(px);
        const int   iy0 = (int)y0f,   ix0 = (int)x0f;
        const float wy1 = py - y0f,   wx1 = px - x0f;
        const float wy0 = 1.f - wy1,  wx0 = 1.f - wx1;
        const bool vy0 = (iy0   >= 0) & (iy0   < HH);
        const bool vy1 = (iy0+1 >= 0) & (iy0+1 < HH);
        const bool vx0 = (ix0   >= 0) & (ix0   < WW);
        const bool vx1 = (ix0+1 >= 0) & (ix0+1 < WW);
        const int cy0 = min(max(iy0,   0), HH-1), cy1 = min(max(iy0+1, 0), HH-1);
        const int cx0 = min(max(ix0,   0), WW-1), cx1 = min(max(ix0+1, 0), WW-1);
        const int i0 = cy0*WW+cx0; const float w0 = wy0*wx0*((vy0&vx0) ? mk : 0.f);
        const int i1 = cy0*WW+cx1; const float w1 = wy0*wx1*((vy0&vx1) ? mk : 0.f);
        const int i2 = cy1*WW+cx0; const float w2 = wy1*wx0*((vy1&vx0) ? mk : 0.f);
        const int i3 = cy1*WW+cx1; const float w3 = wy1*wx1*((vy1&vx1) ? mk : 0.f);

        #pragma unroll
        for (int cb = 0; cb < 8; ++cb) {
            union { half8 v; _Float16 e[8]; } u;
            #pragma unroll
            for (int j = 0; j < 8; ++j) {
                const float* xc = xb + (cb*8 + j)*HWSZ;
                float s = w0*xc[i0] + w1*xc[i1] + w2*xc[i2] + w3*xc[i3];
                u.e[j] = (_Float16)s;
            }
            *(half8*)&A_sh[tid][cb*8] = u.v;
        }
        __syncthreads();
        #pragma unroll
        for (int ks = 0; ks < 2; ++ks) {
            half8 bf[4];
            #pragma unroll
            for (int nt = 0; nt < 4; ++nt)
                bf[nt] = *(const half8*)&Wd_sh[nt*16 + l15][ks*32 + quad*8];
            #pragma unroll
            for (int mt = 0; mt < 4; ++mt) {
                half8 af = *(const half8*)&A_sh[wv*64 + mt*16 + l15][ks*32 + quad*8];
                #pragma unroll
                for (int nt = 0; nt < 4; ++nt)
                    acc[mt][nt] = __builtin_amdgcn_mfma_f32_16x16x32_f16(af, bf[nt], acc[mt][nt], 0, 0, 0);
            }
        }
        __syncthreads();
    }

    // epilogue: 4 chunks of 16 output channels through LDS transpose
    float (*T)[260] = (float (*)[260])&A_sh[0][0];   // [16][260] f32 = 16640 B
    #pragma unroll
    for (int oc = 0; oc < 4; ++oc) {
        #pragma unroll
        for (int mt = 0; mt < 4; ++mt)
            #pragma unroll
            for (int r = 0; r < 4; ++r)
                T[l15][wv*64 + mt*16 + quad*4 + r] = acc[mt][oc][r];
        __syncthreads();
        #pragma unroll
        for (int o16 = 0; o16 < 16; ++o16) {
            int o = oc*16 + o16;
            out[((size_t)b*OO + o)*HWSZ + pix] = T[o16][tid] + db[o];
        }
        __syncthreads();
    }
}

extern "C" void kernel_launch(void* const* d_in, const int* in_sizes, int n_in,
                              void* d_out, int out_size, void* d_ws, size_t ws_size,
                              hipStream_t stream) {
    const float* x   = (const float*)d_in[0];
    const float* p_w = (const float*)d_in[1];
    const float* p_b = (const float*)d_in[2];
    const float* m_w = (const float*)d_in[3];
    const float* m_b = (const float*)d_in[4];
    const float* dw  = (const float*)d_in[5];
    const float* db  = (const float*)d_in[6];

    float* out        = (float*)d_out;             // (B,O,H,W)
    float* offset_out = out + (size_t)BB*OO*HWSZ;  // (B,18,H,W)

    _Float16* Wp     = (_Float16*)d_ws;
    _Float16* Wd     = Wp + WP_ELEMS;
    _Float16* mask_h = Wd + WD_ELEMS;              // (B,9,H,W) f16

    repack<<<dim3((WP_ELEMS + WD_ELEMS + 255)/256), 256, 0, stream>>>(p_w, m_w, dw, Wp, Wd);

    dim3 g(HWSZ/256, BB);
    dcn_offmask<<<g, 256, 0, stream>>>(x, Wp, p_b, m_b, offset_out, mask_h);
    dcn_deform <<<g, 256, 0, stream>>>(x, offset_out, mask_h, Wd, db, out);
}

// Round 4
// 232.108 us; speedup vs baseline: 12.6023x; 1.7293x over previous
//
#include <hip/hip_runtime.h>
#include <math.h>

#define KK 9
#define BB 8
#define CC 64
#define OO 64
#define HH 128
#define WW 128
#define HWSZ (HH*WW)

typedef _Float16 half8 __attribute__((ext_vector_type(8)));
typedef float    floatx4 __attribute__((ext_vector_type(4)));

// ws layout (f16): Wp[32][576] | Wd[9][64][64] | x_h[B][HW][64]
#define WP_ELEMS (32*576)
#define WD_ELEMS (9*64*64)
#define XH_ELEMS ((size_t)BB*HWSZ*64)

// ---------------- repack weights to f16, MFMA-friendly layouts ----------------
__global__ __launch_bounds__(256) void repack(
    const float* __restrict__ p_w, const float* __restrict__ m_w,
    const float* __restrict__ d_w, _Float16* __restrict__ Wp, _Float16* __restrict__ Wd)
{
    int i = blockIdx.x*256 + threadIdx.x;
    if (i < WP_ELEMS) {
        int n = i / 576, r = i % 576;
        int k = r >> 6, c = r & 63;          // K-index = k*64 + c (tap-major)
        float v = 0.f;
        if (n < 18)      v = p_w[(n*CC + c)*KK + k];
        else if (n < 27) v = m_w[((n-18)*CC + c)*KK + k];
        Wp[i] = (_Float16)v;
    } else if (i < WP_ELEMS + WD_ELEMS) {
        int j = i - WP_ELEMS;
        int k = j / 4096, r = j % 4096, o = r >> 6, c = r & 63;  // Wd[k][o][c]
        Wd[j] = (_Float16)d_w[(o*CC + c)*KK + k];
    }
}

// ---------------- convert x (fp32 NCHW) -> x_h (f16, [b][pix][c]) ----------------
__global__ __launch_bounds__(256) void convert_x(
    const float* __restrict__ x, _Float16* __restrict__ x_h)
{
    const int pix = blockIdx.x*256 + threadIdx.x;
    const int b   = blockIdx.y;
    const float* xp = x + (size_t)b*CC*HWSZ + pix;
    _Float16* dst  = x_h + ((size_t)b*HWSZ + pix)*64;
    #pragma unroll
    for (int cb = 0; cb < 8; ++cb) {
        union { half8 v; _Float16 e[8]; } u;
        #pragma unroll
        for (int j = 0; j < 8; ++j) u.e[j] = (_Float16)xp[(cb*8+j)*HWSZ];
        *(half8*)(dst + cb*8) = u.v;
    }
}

// ---------------- fully fused DCNv2 via MFMA ----------------
// flat grid 512 blocks; b = blk & 7 (XCD-locality swizzle), 256 px/block
template<bool CHL>
__global__ __launch_bounds__(256, 2) void dcn_fused(
    const float* __restrict__ x, const _Float16* __restrict__ x_h,
    const _Float16* __restrict__ Wp, const _Float16* __restrict__ Wd,
    const float* __restrict__ p_b, const float* __restrict__ m_b,
    const float* __restrict__ db,
    float* __restrict__ out, float* __restrict__ offset_out)
{
    __shared__ alignas(16) _Float16 A_sh[256][72];   // 36864 B
    __shared__ alignas(16) _Float16 WM_sh[32*72];    //  4608 B: W_sh[32][72] / mask[9][256]
    __shared__ alignas(16) _Float16 Wd_sh[64][72];   //  9216 B

    const int tid  = threadIdx.x;
    const int wv   = tid >> 6;
    const int lane = tid & 63;
    const int quad = lane >> 4;
    const int l15  = lane & 15;
    const int b    = blockIdx.x & 7;                  // XCD swizzle
    const int pix0 = (blockIdx.x >> 3) * 256;
    const int pix  = pix0 + tid;
    const int h = pix >> 7, w = pix & 127;
    const float* xb = x + (size_t)b*CC*HWSZ;
    const _Float16* xbh = x_h + (size_t)b*HWSZ*64;

    _Float16 (*W_sh)[72] = (_Float16 (*)[72])WM_sh;

    // =============== phase 1: offset(18)+mask(9) conv ===============
    floatx4 accp[4][2];
    #pragma unroll
    for (int mt = 0; mt < 4; ++mt)
        #pragma unroll
        for (int nt = 0; nt < 2; ++nt) accp[mt][nt] = (floatx4)0.f;

    for (int k = 0; k < 9; ++k) {
        {
            int n  = tid >> 3;
            int c0 = (tid & 7) * 8;
            *(half8*)&W_sh[n][c0] = *(const half8*)(Wp + n*576 + k*64 + c0);
        }
        const int hy = h + (k/3) - 1;
        const int wx = w + (k%3) - 1;
        const bool vld = (hy >= 0) & (hy < HH) & (wx >= 0) & (wx < WW);
        if constexpr (CHL) {
            const int ip = vld ? hy*WW + wx : 0;
            const _Float16* xs = xbh + (size_t)ip*64;
            #pragma unroll
            for (int cb = 0; cb < 8; ++cb) {
                half8 v = vld ? *(const half8*)(xs + cb*8) : (half8)(_Float16)0.f;
                *(half8*)&A_sh[tid][cb*8] = v;
            }
        } else {
            const float* xs = xb + hy*WW + wx;
            #pragma unroll
            for (int cb = 0; cb < 8; ++cb) {
                union { half8 v; _Float16 e[8]; } u;
                #pragma unroll
                for (int j = 0; j < 8; ++j)
                    u.e[j] = (_Float16)(vld ? xs[(cb*8+j)*HWSZ] : 0.f);
                *(half8*)&A_sh[tid][cb*8] = u.v;
            }
        }
        __syncthreads();
        #pragma unroll
        for (int ks = 0; ks < 2; ++ks) {
            half8 bf[2];
            #pragma unroll
            for (int nt = 0; nt < 2; ++nt)
                bf[nt] = *(const half8*)&W_sh[nt*16 + l15][ks*32 + quad*8];
            #pragma unroll
            for (int mt = 0; mt < 4; ++mt) {
                half8 af = *(const half8*)&A_sh[wv*64 + mt*16 + l15][ks*32 + quad*8];
                accp[mt][0] = __builtin_amdgcn_mfma_f32_16x16x32_f16(af, bf[0], accp[mt][0], 0, 0, 0);
                accp[mt][1] = __builtin_amdgcn_mfma_f32_16x16x32_f16(af, bf[1], accp[mt][1], 0, 0, 0);
            }
        }
        __syncthreads();
    }

    // epilogue 1: transpose, bias, sigmoid; offsets -> global, mask -> LDS
    float (*T)[260] = (float (*)[260])&A_sh[0][0];
    #pragma unroll
    for (int nt = 0; nt < 2; ++nt) {
        const int ch = nt*16 + l15;
        if (ch < 27) {
            #pragma unroll
            for (int mt = 0; mt < 4; ++mt)
                #pragma unroll
                for (int r = 0; r < 4; ++r)
                    T[ch][wv*64 + mt*16 + quad*4 + r] = accp[mt][nt][r];
        }
    }
    __syncthreads();
    float* offp = offset_out + (size_t)b*18*HWSZ + pix;
    _Float16* M_sh = WM_sh;   // [9][256], aliases W_sh (phase-1 use done)
    #pragma unroll
    for (int k = 0; k < 9; ++k) {
        const float dyk = T[2*k][tid]   + p_b[2*k];
        const float dxk = T[2*k+1][tid] + p_b[2*k+1];
        offp[(2*k  )*HWSZ] = dyk;
        offp[(2*k+1)*HWSZ] = dxk;
        const float mv = T[18+k][tid] + m_b[k];
        M_sh[k*256 + tid] = (_Float16)(1.f / (1.f + expf(-mv)));
    }
    __syncthreads();

    // =============== phase 2: modulated deformable conv ===============
    floatx4 acc[4][4];
    #pragma unroll
    for (int mt = 0; mt < 4; ++mt)
        #pragma unroll
        for (int nt = 0; nt < 4; ++nt) acc[mt][nt] = (floatx4)0.f;

    for (int k = 0; k < 9; ++k) {
        {
            int o  = tid >> 2;
            int c0 = (tid & 3) * 16;
            const _Float16* src = Wd + k*4096 + o*64 + c0;
            *(half8*)&Wd_sh[o][c0]     = *(const half8*)src;
            *(half8*)&Wd_sh[o][c0 + 8] = *(const half8*)(src + 8);
        }
        const float dyk = offp[(2*k  )*HWSZ];
        const float dxk = offp[(2*k+1)*HWSZ];
        const float mk  = (float)M_sh[k*256 + tid];
        const float py = (float)(h - 1 + k/3) + dyk;
        const float px = (float)(w - 1 + k%3) + dxk;
        const float y0f = floorf(py), x0f = floorf(px);
        const int   iy0 = (int)y0f,   ix0 = (int)x0f;
        const float wy1 = py - y0f,   wx1 = px - x0f;
        const float wy0 = 1.f - wy1,  wx0 = 1.f - wx1;
        const bool vy0 = (iy0   >= 0) & (iy0   < HH);
        const bool vy1 = (iy0+1 >= 0) & (iy0+1 < HH);
        const bool vx0 = (ix0   >= 0) & (ix0   < WW);
        const bool vx1 = (ix0+1 >= 0) & (ix0+1 < WW);
        const int cy0 = min(max(iy0,   0), HH-1), cy1 = min(max(iy0+1, 0), HH-1);
        const int cx0 = min(max(ix0,   0), WW-1), cx1 = min(max(ix0+1, 0), WW-1);
        const int i0 = cy0*WW+cx0; const float w0 = wy0*wx0*((vy0&vx0) ? mk : 0.f);
        const int i1 = cy0*WW+cx1; const float w1 = wy0*wx1*((vy0&vx1) ? mk : 0.f);
        const int i2 = cy1*WW+cx0; const float w2 = wy1*wx0*((vy1&vx0) ? mk : 0.f);
        const int i3 = cy1*WW+cx1; const float w3 = wy1*wx1*((vy1&vx1) ? mk : 0.f);

        if constexpr (CHL) {
            const _Float16* p0 = xbh + (size_t)i0*64;
            const _Float16* p1 = xbh + (size_t)i1*64;
            const _Float16* p2 = xbh + (size_t)i2*64;
            const _Float16* p3 = xbh + (size_t)i3*64;
            const _Float16 h0 = (_Float16)w0, h1 = (_Float16)w1,
                           h2 = (_Float16)w2, h3 = (_Float16)w3;
            #pragma unroll
            for (int cb = 0; cb < 8; ++cb) {
                half8 v = *(const half8*)(p0 + cb*8) * h0
                        + *(const half8*)(p1 + cb*8) * h1
                        + *(const half8*)(p2 + cb*8) * h2
                        + *(const half8*)(p3 + cb*8) * h3;
                *(half8*)&A_sh[tid][cb*8] = v;
            }
        } else {
            #pragma unroll
            for (int cb = 0; cb < 8; ++cb) {
                union { half8 v; _Float16 e[8]; } u;
                #pragma unroll
                for (int j = 0; j < 8; ++j) {
                    const float* xc = xb + (cb*8 + j)*HWSZ;
                    u.e[j] = (_Float16)(w0*xc[i0] + w1*xc[i1] + w2*xc[i2] + w3*xc[i3]);
                }
                *(half8*)&A_sh[tid][cb*8] = u.v;
            }
        }
        __syncthreads();
        #pragma unroll
        for (int ks = 0; ks < 2; ++ks) {
            half8 bf[4];
            #pragma unroll
            for (int nt = 0; nt < 4; ++nt)
                bf[nt] = *(const half8*)&Wd_sh[nt*16 + l15][ks*32 + quad*8];
            #pragma unroll
            for (int mt = 0; mt < 4; ++mt) {
                half8 af = *(const half8*)&A_sh[wv*64 + mt*16 + l15][ks*32 + quad*8];
                #pragma unroll
                for (int nt = 0; nt < 4; ++nt)
                    acc[mt][nt] = __builtin_amdgcn_mfma_f32_16x16x32_f16(af, bf[nt], acc[mt][nt], 0, 0, 0);
            }
        }
        __syncthreads();
    }

    // epilogue 2: 4 chunks of 16 output channels via LDS transpose
    float (*T2)[260] = (float (*)[260])&A_sh[0][0];
    #pragma unroll
    for (int oc = 0; oc < 4; ++oc) {
        #pragma unroll
        for (int mt = 0; mt < 4; ++mt)
            #pragma unroll
            for (int r = 0; r < 4; ++r)
                T2[l15][wv*64 + mt*16 + quad*4 + r] = acc[mt][oc][r];
        __syncthreads();
        #pragma unroll
        for (int o16 = 0; o16 < 16; ++o16) {
            int o = oc*16 + o16;
            out[((size_t)b*OO + o)*HWSZ + pix] = T2[o16][tid] + db[o];
        }
        __syncthreads();
    }
}

extern "C" void kernel_launch(void* const* d_in, const int* in_sizes, int n_in,
                              void* d_out, int out_size, void* d_ws, size_t ws_size,
                              hipStream_t stream) {
    const float* x   = (const float*)d_in[0];
    const float* p_w = (const float*)d_in[1];
    const float* p_b = (const float*)d_in[2];
    const float* m_w = (const float*)d_in[3];
    const float* m_b = (const float*)d_in[4];
    const float* dw  = (const float*)d_in[5];
    const float* db  = (const float*)d_in[6];

    float* out        = (float*)d_out;             // (B,O,H,W)
    float* offset_out = out + (size_t)BB*OO*HWSZ;  // (B,18,H,W)

    _Float16* Wp  = (_Float16*)d_ws;
    _Float16* Wd  = Wp + WP_ELEMS;
    _Float16* x_h = Wd + WD_ELEMS;

    repack<<<dim3((WP_ELEMS + WD_ELEMS + 255)/256), 256, 0, stream>>>(p_w, m_w, dw, Wp, Wd);

    const size_t need = (size_t)(WP_ELEMS + WD_ELEMS + XH_ELEMS) * sizeof(_Float16);
    if (ws_size >= need) {
        convert_x<<<dim3(HWSZ/256, BB), 256, 0, stream>>>(x, x_h);
        dcn_fused<true><<<dim3(512), 256, 0, stream>>>(x, x_h, Wp, Wd, p_b, m_b, db, out, offset_out);
    } else {
        dcn_fused<false><<<dim3(512), 256, 0, stream>>>(x, x_h, Wp, Wd, p_b, m_b, db, out, offset_out);
    }
}

// Round 5
// 205.225 us; speedup vs baseline: 14.2532x; 1.1310x over previous
//
#include <hip/hip_runtime.h>
#include <math.h>

#define KK 9
#define BB 8
#define CC 64
#define OO 64
#define HH 128
#define WW 128
#define HWSZ (HH*WW)

typedef _Float16 half8 __attribute__((ext_vector_type(8)));
typedef float    floatx4 __attribute__((ext_vector_type(4)));

// ws layout (f16): Wp[32][576] | Wd[9][64][64] | x_h[B][HW][64]
#define WP_ELEMS (32*576)
#define WD_ELEMS (9*64*64)
#define XH_ELEMS ((size_t)BB*HWSZ*64)

// ---------------- repack weights to f16, MFMA-friendly layouts ----------------
__global__ __launch_bounds__(256) void repack(
    const float* __restrict__ p_w, const float* __restrict__ m_w,
    const float* __restrict__ d_w, _Float16* __restrict__ Wp, _Float16* __restrict__ Wd)
{
    int i = blockIdx.x*256 + threadIdx.x;
    if (i < WP_ELEMS) {
        int n = i / 576, r = i % 576;
        int k = r >> 6, c = r & 63;          // K-index = k*64 + c (tap-major)
        float v = 0.f;
        if (n < 18)      v = p_w[(n*CC + c)*KK + k];
        else if (n < 27) v = m_w[((n-18)*CC + c)*KK + k];
        Wp[i] = (_Float16)v;
    } else if (i < WP_ELEMS + WD_ELEMS) {
        int j = i - WP_ELEMS;
        int k = j / 4096, r = j % 4096, o = r >> 6, c = r & 63;  // Wd[k][o][c]
        Wd[j] = (_Float16)d_w[(o*CC + c)*KK + k];
    }
}

// ---------------- convert x (fp32 NCHW) -> x_h (f16 [b][pix][c]) via LDS transpose ----------------
// block 256, tile = 64 px x 64 ch; coalesced reads AND contiguous stores
__global__ __launch_bounds__(256) void convert_x(
    const float* __restrict__ x, _Float16* __restrict__ x_h)
{
    __shared__ _Float16 sh[64][72];
    const int pix0 = blockIdx.x * 64;
    const int b    = blockIdx.y;
    const int tid  = threadIdx.x;
    const float* xb = x + (size_t)b*CC*HWSZ + pix0;
    {
        const int p     = tid & 63;
        const int cbase = tid >> 6;          // 0..3
        #pragma unroll
        for (int j = 0; j < 16; ++j) {
            const int c = j*4 + cbase;
            sh[p][c] = (_Float16)xb[(size_t)c*HWSZ + p];
        }
    }
    __syncthreads();
    {
        const int p  = tid >> 2;
        const int c0 = (tid & 3) * 16;
        _Float16* dst = x_h + ((size_t)b*HWSZ + pix0 + p)*64 + c0;
        *(half8*)dst       = *(const half8*)&sh[p][c0];
        *(half8*)(dst + 8) = *(const half8*)&sh[p][c0 + 8];
    }
}

// ---------------- fully fused DCNv2 via MFMA ----------------
// flat grid 1024 blocks; b = blk & 7 (XCD swizzle); block = 128 px (one image row),
// 4 waves, each wave owns 32 pixels (mt=2); 2 threads per pixel (channel halves).
template<bool CHL>
__global__ __launch_bounds__(256, 4) void dcn_fused(
    const float* __restrict__ x, const _Float16* __restrict__ x_h,
    const _Float16* __restrict__ Wp, const _Float16* __restrict__ Wd,
    const float* __restrict__ p_b, const float* __restrict__ m_b,
    const float* __restrict__ db,
    float* __restrict__ out, float* __restrict__ offset_out)
{
    __shared__ alignas(16) _Float16 A_sh[128][72];   // 18432 B (also T/T2 fp32 alias)
    __shared__ alignas(16) _Float16 WM_sh[32*72];    //  4608 B (phase-1 weights)
    __shared__ alignas(16) _Float16 Wd_sh[64][72];   //  9216 B

    const int tid   = threadIdx.x;
    const int wv    = tid >> 6;
    const int lane  = tid & 63;
    const int quad  = lane >> 4;
    const int l15   = lane & 15;
    const int b     = blockIdx.x & 7;                 // XCD-locality swizzle
    const int row   = blockIdx.x >> 3;                // image row 0..127
    const int pix0  = row * WW;
    const int p     = tid & 127;                      // pixel within row
    const int chalf = (tid >> 7) * 32;                // channel base 0/32
    const int h = row, w = p;
    const float* xb     = x   + (size_t)b*CC*HWSZ;
    const _Float16* xbh = x_h + (size_t)b*HWSZ*64;

    _Float16 (*W_sh)[72] = (_Float16 (*)[72])WM_sh;

    // =============== phase 1: offset(18)+mask(9) conv ===============
    floatx4 accp[2][2];
    #pragma unroll
    for (int mt = 0; mt < 2; ++mt)
        #pragma unroll
        for (int nt = 0; nt < 2; ++nt) accp[mt][nt] = (floatx4)0.f;

    for (int k = 0; k < 9; ++k) {
        {
            const int n  = tid >> 3;
            const int c0 = (tid & 7) * 8;
            *(half8*)&W_sh[n][c0] = *(const half8*)(Wp + n*576 + k*64 + c0);
        }
        const int hy = h + (k/3) - 1;
        const int wx = w + (k%3) - 1;
        const bool vld = (hy >= 0) & (hy < HH) & (wx >= 0) & (wx < WW);
        if constexpr (CHL) {
            const _Float16* xs = xbh + (size_t)(vld ? hy*WW + wx : 0)*64 + chalf;
            #pragma unroll
            for (int cb = 0; cb < 4; ++cb) {
                half8 v = vld ? *(const half8*)(xs + cb*8) : (half8)(_Float16)0.f;
                *(half8*)&A_sh[p][chalf + cb*8] = v;
            }
        } else {
            const float* xs = xb + hy*WW + wx;
            #pragma unroll
            for (int cb = 0; cb < 4; ++cb) {
                union { half8 v; _Float16 e[8]; } u;
                #pragma unroll
                for (int j = 0; j < 8; ++j)
                    u.e[j] = (_Float16)(vld ? xs[(size_t)(chalf + cb*8 + j)*HWSZ] : 0.f);
                *(half8*)&A_sh[p][chalf + cb*8] = u.v;
            }
        }
        __syncthreads();
        #pragma unroll
        for (int ks = 0; ks < 2; ++ks) {
            half8 bf[2];
            #pragma unroll
            for (int nt = 0; nt < 2; ++nt)
                bf[nt] = *(const half8*)&W_sh[nt*16 + l15][ks*32 + quad*8];
            #pragma unroll
            for (int mt = 0; mt < 2; ++mt) {
                half8 af = *(const half8*)&A_sh[wv*32 + mt*16 + l15][ks*32 + quad*8];
                accp[mt][0] = __builtin_amdgcn_mfma_f32_16x16x32_f16(af, bf[0], accp[mt][0], 0, 0, 0);
                accp[mt][1] = __builtin_amdgcn_mfma_f32_16x16x32_f16(af, bf[1], accp[mt][1], 0, 0, 0);
            }
        }
        __syncthreads();
    }

    // epilogue 1: transpose into LDS, bias+sigmoid, offsets -> regs+global, mask -> regs
    float (*T)[132] = (float (*)[132])&A_sh[0][0];   // 27*132*4 = 14256 B, fits
    #pragma unroll
    for (int nt = 0; nt < 2; ++nt) {
        const int ch = nt*16 + l15;
        if (ch < 27) {
            #pragma unroll
            for (int mt = 0; mt < 2; ++mt)
                #pragma unroll
                for (int r = 0; r < 4; ++r)
                    T[ch][wv*32 + mt*16 + quad*4 + r] = accp[mt][nt][r];
        }
    }
    __syncthreads();

    float dyk[9], dxk[9], mkk[9];
    float* offp = offset_out + (size_t)b*18*HWSZ + pix0;
    #pragma unroll
    for (int k = 0; k < 9; ++k) {
        dyk[k] = T[2*k][p]   + p_b[2*k];
        dxk[k] = T[2*k+1][p] + p_b[2*k+1];
        mkk[k] = 1.f / (1.f + expf(-(T[18+k][p] + m_b[k])));
    }
    if (tid < 128) {
        #pragma unroll
        for (int k = 0; k < 9; ++k) {
            offp[(2*k  )*HWSZ + p] = dyk[k];
            offp[(2*k+1)*HWSZ + p] = dxk[k];
        }
    }
    __syncthreads();

    // =============== phase 2: modulated deformable conv ===============
    floatx4 acc[2][4];
    #pragma unroll
    for (int mt = 0; mt < 2; ++mt)
        #pragma unroll
        for (int nt = 0; nt < 4; ++nt) acc[mt][nt] = (floatx4)0.f;

    #pragma unroll
    for (int k = 0; k < 9; ++k) {
        {
            const int o  = tid >> 2;
            const int c0 = (tid & 3) * 16;
            const _Float16* src = Wd + k*4096 + o*64 + c0;
            *(half8*)&Wd_sh[o][c0]     = *(const half8*)src;
            *(half8*)&Wd_sh[o][c0 + 8] = *(const half8*)(src + 8);
        }
        const float mk = mkk[k];
        const float py = (float)(h - 1 + k/3) + dyk[k];
        const float px = (float)(w - 1 + k%3) + dxk[k];
        const float y0f = floorf(py), x0f = floorf(px);
        const int   iy0 = (int)y0f,   ix0 = (int)x0f;
        const float wy1 = py - y0f,   wx1 = px - x0f;
        const float wy0 = 1.f - wy1,  wx0 = 1.f - wx1;
        const bool vy0 = (iy0   >= 0) & (iy0   < HH);
        const bool vy1 = (iy0+1 >= 0) & (iy0+1 < HH);
        const bool vx0 = (ix0   >= 0) & (ix0   < WW);
        const bool vx1 = (ix0+1 >= 0) & (ix0+1 < WW);
        const int cy0 = min(max(iy0,   0), HH-1), cy1 = min(max(iy0+1, 0), HH-1);
        const int cx0 = min(max(ix0,   0), WW-1), cx1 = min(max(ix0+1, 0), WW-1);
        const int i0 = cy0*WW+cx0; const float w0 = wy0*wx0*((vy0&vx0) ? mk : 0.f);
        const int i1 = cy0*WW+cx1; const float w1 = wy0*wx1*((vy0&vx1) ? mk : 0.f);
        const int i2 = cy1*WW+cx0; const float w2 = wy1*wx0*((vy1&vx0) ? mk : 0.f);
        const int i3 = cy1*WW+cx1; const float w3 = wy1*wx1*((vy1&vx1) ? mk : 0.f);

        if constexpr (CHL) {
            const _Float16* p0 = xbh + (size_t)i0*64 + chalf;
            const _Float16* p1 = xbh + (size_t)i1*64 + chalf;
            const _Float16* p2 = xbh + (size_t)i2*64 + chalf;
            const _Float16* p3 = xbh + (size_t)i3*64 + chalf;
            const _Float16 h0 = (_Float16)w0, h1 = (_Float16)w1,
                           h2 = (_Float16)w2, h3 = (_Float16)w3;
            #pragma unroll
            for (int cb = 0; cb < 4; ++cb) {
                half8 v = *(const half8*)(p0 + cb*8) * h0
                        + *(const half8*)(p1 + cb*8) * h1
                        + *(const half8*)(p2 + cb*8) * h2
                        + *(const half8*)(p3 + cb*8) * h3;
                *(half8*)&A_sh[p][chalf + cb*8] = v;
            }
        } else {
            #pragma unroll
            for (int cb = 0; cb < 4; ++cb) {
                union { half8 v; _Float16 e[8]; } u;
                #pragma unroll
                for (int j = 0; j < 8; ++j) {
                    const float* xc = xb + (size_t)(chalf + cb*8 + j)*HWSZ;
                    u.e[j] = (_Float16)(w0*xc[i0] + w1*xc[i1] + w2*xc[i2] + w3*xc[i3]);
                }
                *(half8*)&A_sh[p][chalf + cb*8] = u.v;
            }
        }
        __syncthreads();
        #pragma unroll
        for (int ks = 0; ks < 2; ++ks) {
            half8 bf[4];
            #pragma unroll
            for (int nt = 0; nt < 4; ++nt)
                bf[nt] = *(const half8*)&Wd_sh[nt*16 + l15][ks*32 + quad*8];
            #pragma unroll
            for (int mt = 0; mt < 2; ++mt) {
                half8 af = *(const half8*)&A_sh[wv*32 + mt*16 + l15][ks*32 + quad*8];
                #pragma unroll
                for (int nt = 0; nt < 4; ++nt)
                    acc[mt][nt] = __builtin_amdgcn_mfma_f32_16x16x32_f16(af, bf[nt], acc[mt][nt], 0, 0, 0);
            }
        }
        __syncthreads();
    }

    // epilogue 2: 4 chunks of 16 output channels via LDS transpose
    float (*T2)[132] = (float (*)[132])&A_sh[0][0];
    #pragma unroll
    for (int oc = 0; oc < 4; ++oc) {
        #pragma unroll
        for (int mt = 0; mt < 2; ++mt)
            #pragma unroll
            for (int r = 0; r < 4; ++r)
                T2[l15][wv*32 + mt*16 + quad*4 + r] = acc[mt][oc][r];
        __syncthreads();
        #pragma unroll
        for (int j = 0; j < 8; ++j) {
            const int idx = tid + j*256;              // 0..2047
            const int o16 = idx >> 7, p2 = idx & 127;
            out[((size_t)b*OO + oc*16 + o16)*HWSZ + pix0 + p2] = T2[o16][p2] + db[oc*16 + o16];
        }
        __syncthreads();
    }
}

extern "C" void kernel_launch(void* const* d_in, const int* in_sizes, int n_in,
                              void* d_out, int out_size, void* d_ws, size_t ws_size,
                              hipStream_t stream) {
    const float* x   = (const float*)d_in[0];
    const float* p_w = (const float*)d_in[1];
    const float* p_b = (const float*)d_in[2];
    const float* m_w = (const float*)d_in[3];
    const float* m_b = (const float*)d_in[4];
    const float* dw  = (const float*)d_in[5];
    const float* db  = (const float*)d_in[6];

    float* out        = (float*)d_out;             // (B,O,H,W)
    float* offset_out = out + (size_t)BB*OO*HWSZ;  // (B,18,H,W)

    _Float16* Wp  = (_Float16*)d_ws;
    _Float16* Wd  = Wp + WP_ELEMS;
    _Float16* x_h = Wd + WD_ELEMS;

    repack<<<dim3((WP_ELEMS + WD_ELEMS + 255)/256), 256, 0, stream>>>(p_w, m_w, dw, Wp, Wd);

    const size_t need = (size_t)(WP_ELEMS + WD_ELEMS + XH_ELEMS) * sizeof(_Float16);
    if (ws_size >= need) {
        convert_x<<<dim3(HWSZ/64, BB), 256, 0, stream>>>(x, x_h);
        dcn_fused<true><<<dim3(128*BB), 256, 0, stream>>>(x, x_h, Wp, Wd, p_b, m_b, db, out, offset_out);
    } else {
        dcn_fused<false><<<dim3(128*BB), 256, 0, stream>>>(x, x_h, Wp, Wd, p_b, m_b, db, out, offset_out);
    }
}